// Round 16
// baseline (673.051 us; speedup 1.0000x reference)
//
#include <hip/hip_runtime.h>
#include <hip/hip_bf16.h>
#include <cmath>

using bf16 = __hip_bfloat16;
typedef __bf16 bf16x8 __attribute__((ext_vector_type(8)));
typedef __bf16 bf16x4 __attribute__((ext_vector_type(4)));
typedef float f32x4 __attribute__((ext_vector_type(4)));

constexpr int D = 256;
constexpr int LSRC = 32400;
constexpr int NB = 2;
constexpr int LQ = 300;
constexpr int NDET = 200;
constexpr int MS = NB * LSRC;         // 64800
constexpr int MQ = NB * LQ;           // 600
constexpr int RP_STRIDE = LSRC + LQ;  // 32700
constexpr float IMGW = 180.f, IMGH = 180.f;
constexpr int IW = 180, IH = 180;

constexpr long long OFF_Q  = 0;
constexpr long long OFF_S  = (long long)MQ * D;
constexpr long long OFF_GD = OFF_S + (long long)MS * D;
constexpr long long OFF_GS = OFF_GD + (long long)MS * D;

__device__ inline void gload16(const void* g, void* l) {
  __builtin_amdgcn_global_load_lds(
      (const __attribute__((address_space(1))) void*)g,
      (__attribute__((address_space(3))) void*)l, 16, 0, 0);
}

// bijective XCD swizzle (m204)
__device__ inline int xcd_swz(int b, int nwg) {
  int q = nwg >> 3, r = nwg & 7;
  int xcd = b & 7, i = b >> 3;
  return (xcd < r ? xcd * (q + 1) : r * (q + 1) + (xcd - r) * q) + i;
}

// dynamic-dtype 8-element row load (isb: bf16, else f32) -> bf16x8
__device__ inline bf16x8 ld8_dyn(const void* p, size_t off, bool isb) {
  if (isb) return *(const bf16x8*)((const __bf16*)p + off);
  bf16x8 r;
  const float* f = (const float*)p + off;
#pragma unroll
  for (int j = 0; j < 8; ++j) r[j] = (__bf16)f[j];
  return r;
}

// dynamic-dtype 8-element load -> f32[8] (no rounding)
__device__ inline void ld8f_dyn(const void* p, size_t off, bool isb, float* o) {
  if (isb) {
    bf16x8 x = *(const bf16x8*)((const __bf16*)p + off);
#pragma unroll
    for (int j = 0; j < 8; ++j) o[j] = (float)x[j];
  } else {
    const float* f = (const float*)p + off;
#pragma unroll
    for (int j = 0; j < 8; ++j) o[j] = f[j];
  }
}

// (a+b) with f32 add then bf16 round (matches cvt_add numerics)
__device__ inline bf16x8 ld8_add_dyn(const void* a, const void* b, size_t off, bool isb) {
  bf16x8 r;
  if (isb) {
    bf16x8 x = *(const bf16x8*)((const __bf16*)a + off);
    bf16x8 y = *(const bf16x8*)((const __bf16*)b + off);
#pragma unroll
    for (int j = 0; j < 8; ++j) r[j] = (__bf16)((float)x[j] + (float)y[j]);
  } else {
    const float* fa = (const float*)a + off;
    const float* fb = (const float*)b + off;
#pragma unroll
    for (int j = 0; j < 8; ++j) r[j] = (__bf16)(fa[j] + fb[j]);
  }
  return r;
}

// ---------- dtype detection ----------
__global__ void detect_kernel(const void* g, int* flag) {
  *flag = (*(const unsigned*)g == 0x3F803F80u) ? 1 : 0;
}

// ---------- batched input conversion ----------
struct CvtEnt { const void* src; void* dst; int n; int f32out; };
struct CvtBatch { CvtEnt e[48]; int blk0[49]; int cnt; };

__global__ __launch_bounds__(256) void cvt_batch_kernel(CvtBatch cb, const int* __restrict__ flag) {
  int bid = blockIdx.x;
  int i = 0;
  for (int j = 1; j < cb.cnt; ++j) if (cb.blk0[j] <= bid) i = j;
  const CvtEnt en = cb.e[i];
  int idx = (bid - cb.blk0[i]) * 2048 + threadIdx.x * 8;
  if (idx >= en.n) return;
  const bool isb = (*flag != 0);
  if (en.f32out) {
    float v[8];
    if (isb) {
      bf16x8 x = *(const bf16x8*)((const __bf16*)en.src + idx);
#pragma unroll
      for (int j = 0; j < 8; ++j) v[j] = (float)x[j];
    } else {
      const float* s = (const float*)en.src + idx;
#pragma unroll
      for (int j = 0; j < 8; ++j) v[j] = s[j];
    }
    float* o = (float*)en.dst + idx;
#pragma unroll
    for (int j = 0; j < 8; ++j) o[j] = v[j];
  } else {
    if (isb) {
      uint4 x = *(const uint4*)((const char*)en.src + (size_t)idx * 2);
      *(uint4*)((char*)en.dst + (size_t)idx * 2) = x;
    } else {
      const float* s = (const float*)en.src + idx;
      bf16x8 o;
#pragma unroll
      for (int j = 0; j < 8; ++j) o[j] = (__bf16)s[j];
      *(bf16x8*)((__bf16*)en.dst + idx) = o;
    }
  }
}

__global__ __launch_bounds__(256) void cvt_add(const void* __restrict__ a, const void* __restrict__ b,
                                               const int* __restrict__ flag,
                                               bf16* __restrict__ a_b, bf16* __restrict__ b_b,
                                               bf16* __restrict__ sum, int n8) {
  int i = blockIdx.x * 256 + threadIdx.x;
  if (i >= n8) return;
  const bool isb = (*flag != 0);
  float va[8], vb[8];
  bf16x8 ab, bb;
  if (isb) {
    ab = *(const bf16x8*)((const __bf16*)a + (size_t)i * 8);
    bb = *(const bf16x8*)((const __bf16*)b + (size_t)i * 8);
#pragma unroll
    for (int j = 0; j < 8; ++j) { va[j] = (float)ab[j]; vb[j] = (float)bb[j]; }
  } else {
    const float* pa = (const float*)a + (size_t)i * 8;
    const float* pb = (const float*)b + (size_t)i * 8;
#pragma unroll
    for (int j = 0; j < 8; ++j) { va[j] = pa[j]; vb[j] = pb[j]; ab[j] = (__bf16)va[j]; bb[j] = (__bf16)vb[j]; }
  }
  bf16x8 sb;
#pragma unroll
  for (int j = 0; j < 8; ++j) sb[j] = (__bf16)(va[j] + vb[j]);
  if (a_b) *(bf16x8*)((__bf16*)a_b + (size_t)i * 8) = ab;
  if (b_b) *(bf16x8*)((__bf16*)b_b + (size_t)i * 8) = bb;
  *(bf16x8*)((__bf16*)sum + (size_t)i * 8) = sb;
}

// ---------- GEMM 64x64 tile, BK=64, XCD swizzle ----------
template<int ACT, int OUTB, int RESM>
__global__ __launch_bounds__(256, 3) void gemm_bt(
    const bf16* __restrict__ A, int lda,
    const bf16* __restrict__ Wt,
    const bf16* __restrict__ bias,
    const void* __restrict__ res,
    void* __restrict__ out, int ldo,
    int M, int N, int K)
{
  __shared__ __bf16 As[2][64 * 32];
  __shared__ __bf16 Bs[2][64 * 32];
  const int gy = gridDim.y;
  const int nwg = gridDim.x * gy;
  const int t = xcd_swz(blockIdx.y * gridDim.x + blockIdx.x, nwg);
  const int m0 = (t / gy) * 64;
  const int n0 = (t % gy) * 64;
  const int tid = threadIdx.x;
  const int lane = tid & 63, wid = tid >> 6;
  const int wm = (wid >> 1) * 32, wn = (wid & 1) * 32;
  f32x4 acc[2][2] = {};
  const int lr = tid >> 2;
  const int lc = (tid & 3) * 8;
  const bf16* Ap = A + (size_t)(m0 + lr) * lda + lc;
  const bf16* Wp = Wt + (size_t)(n0 + lr) * K + lc;
  const int fr = lane & 15, ks = (lane >> 4) * 8;

  for (int k0 = 0; k0 < K; k0 += 64) {
    __syncthreads();
#pragma unroll
    for (int kk = 0; kk < 2; ++kk) {
      const int kc = k0 + kk * 32;
      gload16((const __bf16*)Ap + kc, &As[kk][8 * tid]);
      gload16((const __bf16*)Wp + kc, &Bs[kk][8 * tid]);
    }
    __syncthreads();
#pragma unroll
    for (int kk = 0; kk < 2; ++kk) {
      bf16x8 a0 = *(const bf16x8*)&As[kk][(wm + fr) * 32 + ks];
      bf16x8 a1 = *(const bf16x8*)&As[kk][(wm + 16 + fr) * 32 + ks];
      bf16x8 b0 = *(const bf16x8*)&Bs[kk][(wn + fr) * 32 + ks];
      bf16x8 b1 = *(const bf16x8*)&Bs[kk][(wn + 16 + fr) * 32 + ks];
      acc[0][0] = __builtin_amdgcn_mfma_f32_16x16x32_bf16(a0, b0, acc[0][0], 0, 0, 0);
      acc[0][1] = __builtin_amdgcn_mfma_f32_16x16x32_bf16(a0, b1, acc[0][1], 0, 0, 0);
      acc[1][0] = __builtin_amdgcn_mfma_f32_16x16x32_bf16(a1, b0, acc[1][0], 0, 0, 0);
      acc[1][1] = __builtin_amdgcn_mfma_f32_16x16x32_bf16(a1, b1, acc[1][1], 0, 0, 0);
    }
  }

  const int rq = (lane >> 4) * 4;
#pragma unroll
  for (int fm = 0; fm < 2; ++fm)
#pragma unroll
  for (int fn = 0; fn < 2; ++fn) {
    int ncol = n0 + wn + fn * 16 + fr;
    if (ncol >= N) continue;
    float bvs = (float)bias[ncol];
#pragma unroll
    for (int i = 0; i < 4; ++i) {
      int mrow = m0 + wm + fm * 16 + rq + i;
      if (mrow >= M) continue;
      float v = acc[fm][fn][i] + bvs;
      if (RESM == 1) v += (float)((const bf16*)res)[(size_t)mrow * ldo + ncol];
      else if (RESM == 2) v += ((const float*)res)[(size_t)mrow * ldo + ncol];
      if (ACT == 1) v = fmaxf(v, 0.f);
      else if (ACT == 2) v = 0.5f * v * (1.f + erff(v * 0.7071067811865476f));
      else if (ACT == 3) v = 1.f / (1.f + __expf(-v));
      if (OUTB) ((bf16*)out)[(size_t)mrow * ldo + ncol] = (bf16)v;
      else ((float*)out)[(size_t)mrow * ldo + ncol] = v;
    }
  }
}

// ---------- GEMM 64x64 tile: A = A1 + A2 (reg-staged, row-clamped, dtype-dyn) ----------
template<int ADYN>
__global__ __launch_bounds__(256, 3) void gemm_bt_add(
    const void* __restrict__ A1, const void* __restrict__ A2, int lda,
    const bf16* __restrict__ Wt, const bf16* __restrict__ bias,
    float* __restrict__ out, int ldo, int M, int N, int K,
    const int* __restrict__ flagp)
{
  __shared__ __bf16 As[2][64 * 32];
  __shared__ __bf16 Bs[2][64 * 32];
  const int gy = gridDim.y;
  const int nwg = gridDim.x * gy;
  const int t = xcd_swz(blockIdx.y * gridDim.x + blockIdx.x, nwg);
  const int m0 = (t / gy) * 64;
  const int n0 = (t % gy) * 64;
  const int tid = threadIdx.x;
  const int lane = tid & 63, wid = tid >> 6;
  const int wm = (wid >> 1) * 32, wn = (wid & 1) * 32;
  f32x4 acc[2][2] = {};
  const int lr = tid >> 2;
  const int lc = (tid & 3) * 8;
  const int ar = min(m0 + lr, M - 1);
  const size_t abase = (size_t)ar * lda + lc;
  const bf16* Wp = Wt + (size_t)(n0 + lr) * K + lc;
  const bool isb = ADYN ? (*flagp != 0) : true;
  const int fr = lane & 15, ks = (lane >> 4) * 8;

  for (int k0 = 0; k0 < K; k0 += 64) {
    bf16x8 av[2];
#pragma unroll
    for (int kk = 0; kk < 2; ++kk)
      av[kk] = ld8_add_dyn(A1, A2, abase + k0 + kk * 32, isb);
    __syncthreads();
#pragma unroll
    for (int kk = 0; kk < 2; ++kk) {
      *(bf16x8*)&As[kk][8 * tid] = av[kk];
      gload16((const __bf16*)Wp + k0 + kk * 32, &Bs[kk][8 * tid]);
    }
    __syncthreads();
#pragma unroll
    for (int kk = 0; kk < 2; ++kk) {
      bf16x8 a0 = *(const bf16x8*)&As[kk][(wm + fr) * 32 + ks];
      bf16x8 a1 = *(const bf16x8*)&As[kk][(wm + 16 + fr) * 32 + ks];
      bf16x8 b0 = *(const bf16x8*)&Bs[kk][(wn + fr) * 32 + ks];
      bf16x8 b1 = *(const bf16x8*)&Bs[kk][(wn + 16 + fr) * 32 + ks];
      acc[0][0] = __builtin_amdgcn_mfma_f32_16x16x32_bf16(a0, b0, acc[0][0], 0, 0, 0);
      acc[0][1] = __builtin_amdgcn_mfma_f32_16x16x32_bf16(a0, b1, acc[0][1], 0, 0, 0);
      acc[1][0] = __builtin_amdgcn_mfma_f32_16x16x32_bf16(a1, b0, acc[1][0], 0, 0, 0);
      acc[1][1] = __builtin_amdgcn_mfma_f32_16x16x32_bf16(a1, b1, acc[1][1], 0, 0, 0);
    }
  }

  const int rq = (lane >> 4) * 4;
#pragma unroll
  for (int fm = 0; fm < 2; ++fm)
#pragma unroll
  for (int fn = 0; fn < 2; ++fn) {
    int ncol = n0 + wn + fn * 16 + fr;
    if (ncol >= N) continue;
    float bvs = (float)bias[ncol];
#pragma unroll
    for (int i = 0; i < 4; ++i) {
      int mrow = m0 + wm + fm * 16 + rq + i;
      if (mrow >= M) continue;
      out[(size_t)mrow * ldo + ncol] = acc[fm][fn][i] + bvs;
    }
  }
}

// ---------- GEMM 128x128 tile, BK=64, XCD swizzle (A via gload16) ----------
template<int ACT, int OUTB, int RESM, int EMIT>
__global__ __launch_bounds__(256, 3) void gemm128(
    const bf16* __restrict__ A, int lda,
    const bf16* __restrict__ Wt,
    const bf16* __restrict__ bias,
    const void* __restrict__ res,
    void* __restrict__ out, int ldo,
    int M, int N, int K,
    const int* __restrict__ flagp, void* __restrict__ ob, long long eoff)
{
  __shared__ __bf16 As[2][128 * 32];
  __shared__ __bf16 Bs[2][128 * 32];
  const int gy = gridDim.y;
  const int nwg = gridDim.x * gy;
  const int t = xcd_swz(blockIdx.y * gridDim.x + blockIdx.x, nwg);
  const int m0 = (t / gy) * 128;
  const int n0 = (t % gy) * 128;
  const int tid = threadIdx.x;
  const int lane = tid & 63, wid = tid >> 6;
  const int wr = (wid >> 1) * 64, wc = (wid & 1) * 64;
  const int fr = lane & 15, ks = (lane >> 4) * 8;
  f32x4 acc[4][4] = {};

  const int srow = tid >> 2;
  const int scol = (tid & 3) * 8;
  const bf16* Ap0 = A + (size_t)(m0 + srow) * lda + scol;
  const bf16* Ap1 = A + (size_t)(m0 + 64 + srow) * lda + scol;
  const bf16* Bp0 = Wt + (size_t)(n0 + srow) * K + scol;
  const bf16* Bp1 = Wt + (size_t)(n0 + 64 + srow) * K + scol;

  for (int k0 = 0; k0 < K; k0 += 64) {
    __syncthreads();
#pragma unroll
    for (int kk = 0; kk < 2; ++kk) {
      const int kc = k0 + kk * 32;
      gload16((const __bf16*)Ap0 + kc, &As[kk][8 * tid]);
      gload16((const __bf16*)Ap1 + kc, &As[kk][64 * 32 + 8 * tid]);
      gload16((const __bf16*)Bp0 + kc, &Bs[kk][8 * tid]);
      gload16((const __bf16*)Bp1 + kc, &Bs[kk][64 * 32 + 8 * tid]);
    }
    __syncthreads();
#pragma unroll
    for (int kk = 0; kk < 2; ++kk) {
      bf16x8 af[4], bfv[4];
#pragma unroll
      for (int m = 0; m < 4; ++m) af[m]  = *(const bf16x8*)&As[kk][(wr + m * 16 + fr) * 32 + ks];
#pragma unroll
      for (int n = 0; n < 4; ++n) bfv[n] = *(const bf16x8*)&Bs[kk][(wc + n * 16 + fr) * 32 + ks];
#pragma unroll
      for (int m = 0; m < 4; ++m)
#pragma unroll
        for (int n = 0; n < 4; ++n)
          acc[m][n] = __builtin_amdgcn_mfma_f32_16x16x32_bf16(af[m], bfv[n], acc[m][n], 0, 0, 0);
    }
  }

  const bool isb = EMIT ? (*flagp != 0) : false;
  const int rq = (lane >> 4) * 4;
#pragma unroll
  for (int m = 0; m < 4; ++m) {
    const int mb = m0 + wr + m * 16 + rq;
#pragma unroll
    for (int n = 0; n < 4; ++n) {
      const int ncol = n0 + wc + n * 16 + fr;
      const float bvs = (float)bias[ncol];
#pragma unroll
      for (int i = 0; i < 4; ++i) {
        const int mrow = mb + i;
        if (mrow >= M) continue;
        float v = acc[m][n][i] + bvs;
        if (RESM == 1) v += (float)((const bf16*)res)[(size_t)mrow * ldo + ncol];
        else if (RESM == 2) v += ((const float*)res)[(size_t)mrow * ldo + ncol];
        if (ACT == 1) v = fmaxf(v, 0.f);
        else if (ACT == 2) v = 0.5f * v * (1.f + erff(v * 0.7071067811865476f));
        else if (ACT == 3) v = 1.f / (1.f + __expf(-v));
        if (OUTB) ((bf16*)out)[(size_t)mrow * ldo + ncol] = (bf16)v;
        else ((float*)out)[(size_t)mrow * ldo + ncol] = v;
        if (EMIT) {
          long long eo = eoff + (long long)mrow * ldo + ncol;
          if (isb) ((__bf16*)ob)[eo] = (__bf16)v;
          else ((float*)ob)[eo] = v;
        }
      }
    }
  }
}

// ---------- Gate pair: z in {det,seg}; A = proj + z*256; sigmoid; d_out only ----------
__global__ __launch_bounds__(256, 3) void gemm_gate2(
    const bf16* __restrict__ proj,     // [M,512]
    const bf16* __restrict__ W0, const bf16* __restrict__ b0,
    const bf16* __restrict__ W1, const bf16* __restrict__ b1,
    void* __restrict__ ob, long long eo0, long long eo1,
    int M, const int* __restrict__ flagp)
{
  constexpr int K = 256, ldaP = 512;
  __shared__ __bf16 As[2][128 * 32];
  __shared__ __bf16 Bs[2][128 * 32];
  const bf16* Wt = blockIdx.z ? W1 : W0;
  const bf16* bias = blockIdx.z ? b1 : b0;
  const long long eoff = blockIdx.z ? eo1 : eo0;
  const bf16* A = proj + (blockIdx.z ? 256 : 0);
  const int gy = gridDim.y;
  const int nwg = gridDim.x * gy;
  const int t = xcd_swz(blockIdx.y * gridDim.x + blockIdx.x, nwg);
  const int m0 = (t / gy) * 128;
  const int n0 = (t % gy) * 128;
  const int tid = threadIdx.x;
  const int lane = tid & 63, wid = tid >> 6;
  const int wr = (wid >> 1) * 64, wc = (wid & 1) * 64;
  const int fr = lane & 15, ks = (lane >> 4) * 8;
  f32x4 acc[4][4] = {};

  const int srow = tid >> 2;
  const int scol = (tid & 3) * 8;
  const bf16* Ap0 = A + (size_t)(m0 + srow) * ldaP + scol;
  const bf16* Ap1 = A + (size_t)(m0 + 64 + srow) * ldaP + scol;
  const bf16* Bp0 = Wt + (size_t)(n0 + srow) * K + scol;
  const bf16* Bp1 = Wt + (size_t)(n0 + 64 + srow) * K + scol;

  for (int k0 = 0; k0 < K; k0 += 64) {
    __syncthreads();
#pragma unroll
    for (int kk = 0; kk < 2; ++kk) {
      const int kc = k0 + kk * 32;
      gload16((const __bf16*)Ap0 + kc, &As[kk][8 * tid]);
      gload16((const __bf16*)Ap1 + kc, &As[kk][64 * 32 + 8 * tid]);
      gload16((const __bf16*)Bp0 + kc, &Bs[kk][8 * tid]);
      gload16((const __bf16*)Bp1 + kc, &Bs[kk][64 * 32 + 8 * tid]);
    }
    __syncthreads();
#pragma unroll
    for (int kk = 0; kk < 2; ++kk) {
      bf16x8 af[4], bfv[4];
#pragma unroll
      for (int m = 0; m < 4; ++m) af[m]  = *(const bf16x8*)&As[kk][(wr + m * 16 + fr) * 32 + ks];
#pragma unroll
      for (int n = 0; n < 4; ++n) bfv[n] = *(const bf16x8*)&Bs[kk][(wc + n * 16 + fr) * 32 + ks];
#pragma unroll
      for (int m = 0; m < 4; ++m)
#pragma unroll
        for (int n = 0; n < 4; ++n)
          acc[m][n] = __builtin_amdgcn_mfma_f32_16x16x32_bf16(af[m], bfv[n], acc[m][n], 0, 0, 0);
    }
  }

  const bool isb = (*flagp != 0);
  const int rq = (lane >> 4) * 4;
#pragma unroll
  for (int m = 0; m < 4; ++m) {
    const int mb = m0 + wr + m * 16 + rq;
#pragma unroll
    for (int n = 0; n < 4; ++n) {
      const int ncol = n0 + wc + n * 16 + fr;
      const float bvs = (float)bias[ncol];
#pragma unroll
      for (int i = 0; i < 4; ++i) {
        const int mrow = mb + i;
        if (mrow >= M) continue;
        float v = 1.f / (1.f + __expf(-(acc[m][n][i] + bvs)));
        long long eo = eoff + (long long)mrow * 256 + ncol;
        if (isb) ((__bf16*)ob)[eo] = (__bf16)v;
        else ((float*)ob)[eo] = v;
      }
    }
  }
}

// ---------- GEMM 128x128, reg-staged A (row-clamped): OP=0 A=S, OP=1 A=S*G ----------
template<int OP, int SDYN, int GDYN>
__global__ __launch_bounds__(256, 3) void gemm128_rs(
    const void* __restrict__ S, const void* __restrict__ gbase,
    long long geo0, long long geo1,
    int lda,
    const bf16* __restrict__ Wt, const bf16* __restrict__ bias,
    bf16* __restrict__ out0, bf16* __restrict__ out1, int ldo,
    int M, int N, int K, const int* __restrict__ flagp)
{
  __shared__ __bf16 As[2][128 * 32];
  __shared__ __bf16 Bs[2][128 * 32];
  const long long geo = blockIdx.z ? geo1 : geo0;
  bf16* out = blockIdx.z ? out1 : out0;
  const int gy = gridDim.y;
  const int nwg = gridDim.x * gy;
  const int t = xcd_swz(blockIdx.y * gridDim.x + blockIdx.x, nwg);
  const int m0 = (t / gy) * 128;
  const int n0 = (t % gy) * 128;
  const int tid = threadIdx.x;
  const int lane = tid & 63, wid = tid >> 6;
  const int wr = (wid >> 1) * 64, wc = (wid & 1) * 64;
  const int fr = lane & 15, ks = (lane >> 4) * 8;
  f32x4 acc[4][4] = {};

  const int srow = tid >> 2;
  const int scol = (tid & 3) * 8;
  const int r0 = min(m0 + srow, M - 1);
  const int r1 = min(m0 + 64 + srow, M - 1);
  const size_t s0off = (size_t)r0 * lda + scol;
  const size_t s1off = (size_t)r1 * lda + scol;
  const bf16* Bp0 = Wt + (size_t)(n0 + srow) * K + scol;
  const bf16* Bp1 = Wt + (size_t)(n0 + 64 + srow) * K + scol;
  const bool isb = (SDYN || GDYN) ? (*flagp != 0) : true;
  const bool isbS = SDYN ? isb : true;
  const bool isbG = GDYN ? isb : true;

  for (int k0 = 0; k0 < K; k0 += 64) {
    bf16x8 a0[2], a1[2];
#pragma unroll
    for (int kk = 0; kk < 2; ++kk) {
      const int kc = kk * 32 + k0;
      bf16x8 s0 = ld8_dyn(S, s0off + kc, isbS);
      bf16x8 s1 = ld8_dyn(S, s1off + kc, isbS);
      if (OP == 1) {
        float g0[8], g1[8];
        ld8f_dyn(gbase, (size_t)geo + s0off + kc, isbG, g0);
        ld8f_dyn(gbase, (size_t)geo + s1off + kc, isbG, g1);
#pragma unroll
        for (int j = 0; j < 8; ++j) {
          a0[kk][j] = (__bf16)((float)s0[j] * g0[j]);
          a1[kk][j] = (__bf16)((float)s1[j] * g1[j]);
        }
      } else {
        a0[kk] = s0;
        a1[kk] = s1;
      }
    }
    __syncthreads();
#pragma unroll
    for (int kk = 0; kk < 2; ++kk) {
      const int kc = kk * 32 + k0;
      *(bf16x8*)&As[kk][8 * tid] = a0[kk];
      *(bf16x8*)&As[kk][64 * 32 + 8 * tid] = a1[kk];
      gload16((const __bf16*)Bp0 + kc, &Bs[kk][8 * tid]);
      gload16((const __bf16*)Bp1 + kc, &Bs[kk][64 * 32 + 8 * tid]);
    }
    __syncthreads();
#pragma unroll
    for (int kk = 0; kk < 2; ++kk) {
      bf16x8 af[4], bfv[4];
#pragma unroll
      for (int m = 0; m < 4; ++m) af[m]  = *(const bf16x8*)&As[kk][(wr + m * 16 + fr) * 32 + ks];
#pragma unroll
      for (int n = 0; n < 4; ++n) bfv[n] = *(const bf16x8*)&Bs[kk][(wc + n * 16 + fr) * 32 + ks];
#pragma unroll
      for (int m = 0; m < 4; ++m)
#pragma unroll
        for (int n = 0; n < 4; ++n)
          acc[m][n] = __builtin_amdgcn_mfma_f32_16x16x32_bf16(af[m], bfv[n], acc[m][n], 0, 0, 0);
    }
  }

  const int rq = (lane >> 4) * 4;
#pragma unroll
  for (int m = 0; m < 4; ++m) {
    const int mb = m0 + wr + m * 16 + rq;
#pragma unroll
    for (int n = 0; n < 4; ++n) {
      const int ncol = n0 + wc + n * 16 + fr;
      const float bvs = (float)bias[ncol];
#pragma unroll
      for (int i = 0; i < 4; ++i) {
        const int mrow = mb + i;
        if (mrow >= M) continue;
        out[(size_t)mrow * ldo + ncol] = (bf16)(acc[m][n][i] + bvs);
      }
    }
  }
}

// ---------- Fused GEMM (N==256) + bias + residual + LayerNorm; BK=64 ----------
template<int RESM, int EMIT, int OUTF>
__global__ __launch_bounds__(256, 3) void gemm_ln(
    const bf16* __restrict__ A, int lda,
    const bf16* __restrict__ Wt,
    const bf16* __restrict__ bias,
    const void* __restrict__ res,
    const bf16* __restrict__ g, const bf16* __restrict__ b,
    bf16* __restrict__ outb, float* __restrict__ outf,
    int M, int K,
    const int* __restrict__ flagp, void* __restrict__ ob, long long eoff)
{
  __shared__ __bf16 As[2][64 * 32];
  __shared__ __bf16 Bs[2][256 * 32];
  __shared__ float redS[4][64], redQ[4][64];
  const int m0 = blockIdx.x * 64;
  const int tid = threadIdx.x, lane = tid & 63, wid = tid >> 6;
  const int wc = wid * 64;
  const int fr = lane & 15, ks = (lane >> 4) * 8;
  f32x4 acc[4][4] = {};
  const int srow = tid >> 2, scol = (tid & 3) * 8;
  const bf16* Ap = A + (size_t)(m0 + srow) * lda + scol;
  const bf16* Bp = Wt + (size_t)srow * K + scol;

  for (int k0 = 0; k0 < K; k0 += 64) {
    __syncthreads();
#pragma unroll
    for (int kk = 0; kk < 2; ++kk) {
      const int kc = k0 + kk * 32;
      gload16((const __bf16*)Ap + kc, &As[kk][8 * tid]);
#pragma unroll
      for (int j = 0; j < 4; ++j)
        gload16((const __bf16*)(Bp + (size_t)j * 64 * K) + kc, &Bs[kk][j * 64 * 32 + 8 * tid]);
    }
    __syncthreads();
#pragma unroll
    for (int kk = 0; kk < 2; ++kk) {
      bf16x8 af[4], bfv[4];
#pragma unroll
      for (int m = 0; m < 4; ++m) af[m]  = *(const bf16x8*)&As[kk][(m * 16 + fr) * 32 + ks];
#pragma unroll
      for (int n = 0; n < 4; ++n) bfv[n] = *(const bf16x8*)&Bs[kk][(wc + n * 16 + fr) * 32 + ks];
#pragma unroll
      for (int m = 0; m < 4; ++m)
#pragma unroll
        for (int n = 0; n < 4; ++n)
          acc[m][n] = __builtin_amdgcn_mfma_f32_16x16x32_bf16(af[m], bfv[n], acc[m][n], 0, 0, 0);
    }
  }

  const int rq = (lane >> 4) * 4;
  const bool fb = (EMIT || RESM == 3) ? (*flagp != 0) : false;
  float bvals[4], gvals[4], bb2[4];
#pragma unroll
  for (int n = 0; n < 4; ++n) {
    bvals[n] = (float)bias[wc + n * 16 + fr];
    gvals[n] = (float)g[wc + n * 16 + fr];
    bb2[n]   = (float)b[wc + n * 16 + fr];
  }
#pragma unroll
  for (int m = 0; m < 4; ++m)
#pragma unroll
  for (int i = 0; i < 4; ++i) {
    const int mrow = m0 + m * 16 + rq + i;
    const int rr = mrow < M ? mrow : M - 1;
#pragma unroll
    for (int n = 0; n < 4; ++n) {
      const size_t ri = (size_t)rr * 256 + wc + n * 16 + fr;
      float r;
      if (RESM == 1) r = (float)((const bf16*)res)[ri];
      else if (RESM == 2) r = ((const float*)res)[ri];
      else r = fb ? (float)((const bf16*)res)[ri] : ((const float*)res)[ri];
      acc[m][n][i] += bvals[n] + r;
    }
    float s = acc[m][0][i] + acc[m][1][i] + acc[m][2][i] + acc[m][3][i];
    float q = acc[m][0][i] * acc[m][0][i] + acc[m][1][i] * acc[m][1][i]
            + acc[m][2][i] * acc[m][2][i] + acc[m][3][i] * acc[m][3][i];
#pragma unroll
    for (int off = 1; off <= 8; off <<= 1) {
      s += __shfl_xor(s, off);
      q += __shfl_xor(q, off);
    }
    if (fr == 0) { redS[wid][m * 16 + rq + i] = s; redQ[wid][m * 16 + rq + i] = q; }
  }
  __syncthreads();
#pragma unroll
  for (int m = 0; m < 4; ++m)
#pragma unroll
  for (int i = 0; i < 4; ++i) {
    const int rl = m * 16 + rq + i;
    const int mrow = m0 + rl;
    if (mrow >= M) continue;
    float ts = redS[0][rl] + redS[1][rl] + redS[2][rl] + redS[3][rl];
    float tq = redQ[0][rl] + redQ[1][rl] + redQ[2][rl] + redQ[3][rl];
    float mean = ts * (1.f / 256.f);
    float var = tq * (1.f / 256.f) - mean * mean;
    float rstd = rsqrtf(var + 1e-5f);
#pragma unroll
    for (int n = 0; n < 4; ++n) {
      const int col = wc + n * 16 + fr;
      float y = (acc[m][n][i] - mean) * rstd * gvals[n] + bb2[n];
      if (outb) outb[(size_t)mrow * 256 + col] = (bf16)y;
      if (OUTF) outf[(size_t)mrow * 256 + col] = y;
      if (EMIT) {
        long long eo = eoff + (long long)mrow * 256 + col;
        if (fb) ((__bf16*)ob)[eo] = (__bf16)y;
        else ((float*)ob)[eo] = y;
      }
    }
  }
}

// ---------- MSDA sampling: 1 wave/query; valA/valB split; optional XCD swizzle ----------
__global__ __launch_bounds__(256) void msda_sample4(
    const float* __restrict__ oa,
    const float* __restrict__ rpf, int rp_base, int qcnt4, int lqrow, int split,
    const bf16* __restrict__ valA, const bf16* __restrict__ valB,
    bf16* __restrict__ out, int swz) {
  int blk = blockIdx.x;
  if (swz) blk = xcd_swz(blk, gridDim.x);
  int b = blk / qcnt4;
  int wid = threadIdx.x >> 6, lane = threadIdx.x & 63;
  int qi = (blk % qcnt4) * 4 + wid;
  size_t row = (size_t)b * lqrow + qi;
  int h = lane >> 3, d0 = (lane & 7) * 4;
  const bf16* val = (qi < split) ? valA : valB;
  const __bf16* vb = (const __bf16*)val + (size_t)b * LSRC * 256 + h * 32 + d0;
  float rx = rpf[((size_t)b * RP_STRIDE + rp_base + qi) * 2 + 0];
  float ry = rpf[((size_t)b * RP_STRIDE + rp_base + qi) * 2 + 1];
  const float* offp = oa + row * 96 + h * 8;
  const float* awp  = oa + row * 96 + 64 + h * 4;
  float a0 = awp[0], a1 = awp[1], a2 = awp[2], a3 = awp[3];
  float mx = fmaxf(fmaxf(a0, a1), fmaxf(a2, a3));
  float e0 = __expf(a0 - mx), e1 = __expf(a1 - mx), e2 = __expf(a2 - mx), e3 = __expf(a3 - mx);
  float rs = 1.f / (e0 + e1 + e2 + e3);
  float aws[4] = { e0 * rs, e1 * rs, e2 * rs, e3 * rs };
  float o0 = 0.f, o1 = 0.f, o2 = 0.f, o3 = 0.f;
#pragma unroll
  for (int p = 0; p < 4; ++p) {
    float x = rx * IMGW + offp[p * 2 + 0] - 0.5f;
    float y = ry * IMGH + offp[p * 2 + 1] - 0.5f;
    float x0f = floorf(x), y0f = floorf(y);
    float lx = x - x0f, ly = y - y0f;
    int x0 = (int)x0f, y0 = (int)y0f;
#pragma unroll
    for (int dy = 0; dy < 2; ++dy)
#pragma unroll
    for (int dx = 0; dx < 2; ++dx) {
      int xi = x0 + dx, yi = y0 + dy;
      if (xi >= 0 && xi < IW && yi >= 0 && yi < IH) {
        float wgt = aws[p] * (dx ? lx : 1.f - lx) * (dy ? ly : 1.f - ly);
        bf16x4 gv = *(const bf16x4*)(vb + (size_t)(yi * IW + xi) * 256);
        o0 += wgt * (float)gv[0]; o1 += wgt * (float)gv[1];
        o2 += wgt * (float)gv[2]; o3 += wgt * (float)gv[3];
      }
    }
  }
  bf16x4 ov;
  ov[0] = (__bf16)o0; ov[1] = (__bf16)o1; ov[2] = (__bf16)o2; ov[3] = (__bf16)o3;
  *(bf16x4*)((__bf16*)out + row * 256 + h * 32 + d0) = ov;
}

// ---------- small MHA: grid = 2*8*75, 4 queries/block ----------
__global__ __launch_bounds__(256) void mha_attn(
    const float* __restrict__ qk,
    const float* __restrict__ v,
    bf16* __restrict__ o) {
  __shared__ float probs[4][304];
  int bh = blockIdx.x / 75;
  int j  = blockIdx.x % 75;
  int b = bh >> 3, h = bh & 7;
  int wid = threadIdx.x >> 6, lane = threadIdx.x & 63;
  const float scale = 0.17677669529663687f;
  int q = j * 4 + wid;
  const float* qv = qk + ((size_t)(b * 300 + q)) * 512 + h * 32;
  float p[5];
  float mx = -1e30f;
#pragma unroll
  for (int s5 = 0; s5 < 5; ++s5) {
    int k = lane + 64 * s5;
    float sacc = -1e30f;
    if (k < 300) {
      const float* kv = qk + ((size_t)(b * 300 + k)) * 512 + 256 + h * 32;
      float sd = 0.f;
#pragma unroll
      for (int dd = 0; dd < 32; ++dd) sd += qv[dd] * kv[dd];
      sacc = sd * scale;
    }
    p[s5] = sacc;
    mx = fmaxf(mx, sacc);
  }
#pragma unroll
  for (int off = 32; off; off >>= 1) mx = fmaxf(mx, __shfl_xor(mx, off));
  float ssum = 0.f;
#pragma unroll
  for (int s5 = 0; s5 < 5; ++s5) {
    p[s5] = (p[s5] > -1e29f) ? __expf(p[s5] - mx) : 0.f;
    ssum += p[s5];
  }
#pragma unroll
  for (int off = 32; off; off >>= 1) ssum += __shfl_xor(ssum, off);
  float rinv = 1.f / ssum;
#pragma unroll
  for (int s5 = 0; s5 < 5; ++s5) {
    int k = lane + 64 * s5;
    if (k < 300) probs[wid][k] = p[s5] * rinv;
  }
  __syncthreads();
  {
    int d = lane & 31, half = lane >> 5;
    float acc = 0.f;
    for (int k = half * 150; k < half * 150 + 150; ++k)
      acc += probs[wid][k] * v[((size_t)(b * 300 + k)) * 256 + h * 32 + d];
    acc += __shfl_xor(acc, 32);
    if (lane < 32) o[((size_t)(b * 300 + q)) * 256 + h * 32 + d] = (bf16)acc;
  }
}

extern "C" void kernel_launch(void* const* d_in, const int* in_sizes, int n_in,
                              void* d_out, int out_size, void* d_ws, size_t ws_size,
                              hipStream_t stream) {
  (void)n_in; (void)out_size; (void)ws_size;
  const size_t SZ = (size_t)MS * D * sizeof(bf16);   // 33,177,600

  char* w = (char*)d_ws;
  auto carve = [&](size_t bytes) { char* p = w; w += (bytes + 255) & ~(size_t)255; return p; };

  int*   flag = (int*)carve(256);
  float* rp_f = (float*)carve((size_t)NB * RP_STRIDE * 2 * 4);

  bf16* wb[51] = {};
  bf16* wcat_s = nullptr; bf16* bcat_s = nullptr;
  bf16* wcat_q = nullptr; bf16* bcat_q = nullptr;
  for (int i = 7; i <= 50; ++i) {
    if (i == 9)       { wcat_s = (bf16*)carve((size_t)96 * 256 * 2); wb[9]  = wcat_s; }
    else if (i == 10) { bcat_s = (bf16*)carve(96 * 2);               wb[10] = bcat_s; }
    else if (i == 11) { wb[11] = wcat_s + 64 * 256; }
    else if (i == 12) { wb[12] = bcat_s + 64; }
    else if (i == 17) { wcat_q = (bf16*)carve((size_t)96 * 256 * 2); wb[17] = wcat_q; }
    else if (i == 18) { bcat_q = (bf16*)carve(96 * 2);               wb[18] = bcat_q; }
    else if (i == 19) { wb[19] = wcat_q + 64 * 256; }
    else if (i == 20) { wb[20] = bcat_q + 64; }
    else wb[i] = (bf16*)carve((size_t)in_sizes[i] * 2);
  }

  bf16* query_b     = (bf16*)carve((size_t)MQ * D * 2);
  bf16* query_pos_b = (bf16*)carve((size_t)MQ * D * 2);
  bf16* qx_q        = (bf16*)carve((size_t)MQ * D * 2);
  bf16* att_q       = (bf16*)carve((size_t)MQ * D * 2);
  bf16* q_x         = (bf16*)carve((size_t)MQ * D * 2);
  bf16* mha_o       = (bf16*)carve((size_t)MQ * D * 2);
  bf16* lnq_b       = (bf16*)carve((size_t)MQ * D * 2);
  bf16* qh          = (bf16*)carve((size_t)MQ * 1024 * 2);
  float* qoffawb    = (float*)carve((size_t)MQ * 96 * 4);
  float* q_res      = (float*)carve((size_t)MQ * D * 4);
  float* qk_f       = (float*)carve((size_t)MQ * 512 * 4);
  float* v_f        = (float*)carve((size_t)MQ * D * 4);

  char* A = carve(SZ);   // srcout (ph2+)
  char* B = carve(SZ);   // offawb (f32 [MS,96])
  char* C = carve(SZ);   // samp -> lnx (in-place)
  char* Dd = carve(SZ);  // val(sa) -> hid(lo) -> proj(lo) -> val_det
  char* E = carve(SZ);   // hid(hi) -> proj(hi) -> val_seg
  carve(512 * 1024);     // tail pad

  const bf16* query     = (const bf16*)d_in[0];
  const bf16* query_pos = (const bf16*)d_in[1];
  const void* src       = d_in[2];
  const void* pos       = d_in[3];

  dim3 blk(256);
  const int GS64  = (MS + 63) / 64;        // 1013
  const int GQ64  = (MQ + 63) / 64;        // 10
  const int G128  = (MS + 127) / 128;      // 507

  // ---- detect + convert ----
  detect_kernel<<<1, 1, 0, stream>>>(d_in[23], flag);
  {
    CvtBatch cb{};
    int nb = 0, cnt = 0;
    auto addcvt = [&](const void* s, void* dst, int n, int f32o) {
      cb.e[cnt] = { s, dst, n, f32o };
      cb.blk0[cnt] = nb;
      nb += (n + 2047) / 2048;
      ++cnt;
    };
    addcvt(d_in[4], rp_f, in_sizes[4], 1);
    for (int i = 7; i <= 50; ++i) addcvt(d_in[i], wb[i], in_sizes[i], 0);
    cb.cnt = cnt;
    cvt_batch_kernel<<<nb, blk, 0, stream>>>(cb, flag);
  }
  cvt_add<<<MQ * D / 8 / 256, blk, 0, stream>>>(query, query_pos, flag, query_b, query_pos_b, qx_q, MQ * D / 8);

  // ---- Phase 1: self MSDA ----
  float* offawb = (float*)B;
  bf16*  val    = (bf16*)Dd;
  gemm_bt_add<1><<<dim3(GS64,2), blk, 0, stream>>>(src, pos, 256, wb[9], wb[10], offawb, 96, MS, 96, 256, flag);
  gemm128_rs<0,1,0><<<dim3(G128,2,1), blk, 0, stream>>>(src, nullptr, 0, 0, 256, wb[7], wb[8], val, nullptr, 256, MS, 256, 256, flag);
  bf16* samp = (bf16*)C;
  msda_sample4<<<NB * (LSRC / 4), blk, 0, stream>>>(offawb, rp_f, 0, LSRC / 4, LSRC, 1 << 30, val, val, samp, 1);
  bf16* lnx = (bf16*)C;
  gemm_ln<3,0,0><<<GS64, blk, 0, stream>>>(samp, 256, wb[13], wb[14], src, wb[23], wb[24],
                                           lnx, nullptr, MS, 256, flag, nullptr, 0);

  // ---- Phase 2: FFN1 in 2 chunks; hid spans Dd+E; FFN2+LN2 fused, emit d_out ----
  bf16* srcout = (bf16*)A;
  {
    const int CH = MS / 2;
    const int GC128 = (CH + 127) / 128;
    const int GC64  = (CH + 63) / 64;
    bf16* hid = (bf16*)Dd;
    for (int c = 0; c < 2; ++c) {
      size_t ro = (size_t)c * CH * 256;
      gemm128<1,1,0,0><<<dim3(GC128,8), blk, 0, stream>>>(lnx + ro, 256, wb[33], wb[34], nullptr, hid, 1024, CH, 1024, 256, nullptr, nullptr, 0);
      gemm_ln<1,1,0><<<GC64, blk, 0, stream>>>(hid, 1024, wb[35], wb[36], lnx + ro, wb[25], wb[26],
                                               srcout + ro, nullptr, CH, 1024, flag, d_out, OFF_S + (long long)ro);
    }
  }

  // ---- Phase 3: tcs proj + gate pair ----
  bf16* proj = (bf16*)Dd;      // 66 MB spans Dd+E
  gemm128<2,1,0,0><<<dim3(G128,4), blk, 0, stream>>>(srcout, 256, wb[41], wb[42], nullptr, proj, 512, MS, 512, 256, nullptr, nullptr, 0);
  gemm_gate2<<<dim3(G128,2,2), blk, 0, stream>>>(proj, wb[43], wb[44], wb[45], wb[46],
                                                 d_out, OFF_GD, OFF_GS, MS, flag);

  // ---- query off/aw ----
  gemm_bt<0,0,0><<<dim3(GQ64,2), blk, 0, stream>>>(qx_q, 256, wb[17], wb[18], nullptr, qoffawb, 96, MQ, 96, 256);

  // ---- Phase 4: gated value GEMMs (z: det/seg; gates from d_out), merged sampler ----
  bf16* val_det = (bf16*)Dd;
  bf16* val_seg = (bf16*)E;
  gemm128_rs<1,0,1><<<dim3(G128,2,2), blk, 0, stream>>>(srcout, d_out, OFF_GD, OFF_GS, 256,
                                                        wb[15], wb[16], val_det, val_seg, 256,
                                                        MS, 256, 256, flag);
  msda_sample4<<<NB * (LQ / 4), blk, 0, stream>>>(qoffawb, rp_f, LSRC, LQ / 4, LQ, NDET, val_det, val_seg, att_q, 0);

  // ---- Phase 5: ca out-proj + normq (fused) ----
  gemm_ln<1,0,1><<<GQ64, blk, 0, stream>>>(att_q, 256, wb[21], wb[22], query_b, wb[27], wb[28],
                                           q_x, q_res, MQ, 256, nullptr, nullptr, 0);

  // ---- Phase 6: query self-attention ----
  gemm_bt_add<0><<<dim3(GQ64,8), blk, 0, stream>>>(q_x, query_pos_b, 256, wb[47], wb[48], qk_f, 512, MQ, 512, 256, flag);
  gemm_bt<0,0,0><<<dim3(GQ64,4), blk, 0, stream>>>(q_x, 256, wb[47] + (size_t)512 * 256, wb[48] + 512, nullptr, v_f, 256, MQ, 256, 256);
  mha_attn<<<NB * 8 * 75, blk, 0, stream>>>(qk_f, v_f, mha_o);
  gemm_ln<2,0,1><<<GQ64, blk, 0, stream>>>(mha_o, 256, wb[49], wb[50], q_res, wb[29], wb[30],
                                           q_x, q_res, MQ, 256, nullptr, nullptr, 0);

  // ---- Phase 7: FFN3 + norm3 (fused, emits query output) ----
  gemm_bt<1,1,0><<<dim3(GQ64,16), blk, 0, stream>>>(q_x, 256, wb[37], wb[38], nullptr, qh, 1024, MQ, 1024, 256);
  gemm_ln<2,1,0><<<GQ64, blk, 0, stream>>>(qh, 1024, wb[39], wb[40], q_res, wb[31], wb[32],
                                           lnq_b, nullptr, MQ, 1024, flag, d_out, OFF_Q);
}

// Round 17
// 664.679 us; speedup vs baseline: 1.0126x; 1.0126x over previous
//
#include <hip/hip_runtime.h>
#include <hip/hip_bf16.h>
#include <cmath>

using bf16 = __hip_bfloat16;
typedef __bf16 bf16x8 __attribute__((ext_vector_type(8)));
typedef __bf16 bf16x4 __attribute__((ext_vector_type(4)));
typedef float f32x4 __attribute__((ext_vector_type(4)));

constexpr int D = 256;
constexpr int LSRC = 32400;
constexpr int NB = 2;
constexpr int LQ = 300;
constexpr int NDET = 200;
constexpr int MS = NB * LSRC;         // 64800
constexpr int MQ = NB * LQ;           // 600
constexpr int RP_STRIDE = LSRC + LQ;  // 32700
constexpr float IMGW = 180.f, IMGH = 180.f;
constexpr int IW = 180, IH = 180;

constexpr long long OFF_Q  = 0;
constexpr long long OFF_S  = (long long)MQ * D;
constexpr long long OFF_GD = OFF_S + (long long)MS * D;
constexpr long long OFF_GS = OFF_GD + (long long)MS * D;

__device__ inline void gload16(const void* g, void* l) {
  __builtin_amdgcn_global_load_lds(
      (const __attribute__((address_space(1))) void*)g,
      (__attribute__((address_space(3))) void*)l, 16, 0, 0);
}

// bijective XCD swizzle (m204)
__device__ inline int xcd_swz(int b, int nwg) {
  int q = nwg >> 3, r = nwg & 7;
  int xcd = b & 7, i = b >> 3;
  return (xcd < r ? xcd * (q + 1) : r * (q + 1) + (xcd - r) * q) + i;
}

// dynamic-dtype 8-element row load (isb: bf16, else f32) -> bf16x8
__device__ inline bf16x8 ld8_dyn(const void* p, size_t off, bool isb) {
  if (isb) return *(const bf16x8*)((const __bf16*)p + off);
  bf16x8 r;
  const float* f = (const float*)p + off;
#pragma unroll
  for (int j = 0; j < 8; ++j) r[j] = (__bf16)f[j];
  return r;
}

// dynamic-dtype 8-element load -> f32[8] (no rounding)
__device__ inline void ld8f_dyn(const void* p, size_t off, bool isb, float* o) {
  if (isb) {
    bf16x8 x = *(const bf16x8*)((const __bf16*)p + off);
#pragma unroll
    for (int j = 0; j < 8; ++j) o[j] = (float)x[j];
  } else {
    const float* f = (const float*)p + off;
#pragma unroll
    for (int j = 0; j < 8; ++j) o[j] = f[j];
  }
}

// (a+b) with f32 add then bf16 round (matches cvt_add numerics)
__device__ inline bf16x8 ld8_add_dyn(const void* a, const void* b, size_t off, bool isb) {
  bf16x8 r;
  if (isb) {
    bf16x8 x = *(const bf16x8*)((const __bf16*)a + off);
    bf16x8 y = *(const bf16x8*)((const __bf16*)b + off);
#pragma unroll
    for (int j = 0; j < 8; ++j) r[j] = (__bf16)((float)x[j] + (float)y[j]);
  } else {
    const float* fa = (const float*)a + off;
    const float* fb = (const float*)b + off;
#pragma unroll
    for (int j = 0; j < 8; ++j) r[j] = (__bf16)(fa[j] + fb[j]);
  }
  return r;
}

// ---------- dtype detection ----------
__global__ void detect_kernel(const void* g, int* flag) {
  *flag = (*(const unsigned*)g == 0x3F803F80u) ? 1 : 0;
}

// ---------- batched input conversion ----------
struct CvtEnt { const void* src; void* dst; int n; int f32out; };
struct CvtBatch { CvtEnt e[48]; int blk0[49]; int cnt; };

__global__ __launch_bounds__(256) void cvt_batch_kernel(CvtBatch cb, const int* __restrict__ flag) {
  int bid = blockIdx.x;
  int i = 0;
  for (int j = 1; j < cb.cnt; ++j) if (cb.blk0[j] <= bid) i = j;
  const CvtEnt en = cb.e[i];
  int idx = (bid - cb.blk0[i]) * 2048 + threadIdx.x * 8;
  if (idx >= en.n) return;
  const bool isb = (*flag != 0);
  if (en.f32out) {
    float v[8];
    if (isb) {
      bf16x8 x = *(const bf16x8*)((const __bf16*)en.src + idx);
#pragma unroll
      for (int j = 0; j < 8; ++j) v[j] = (float)x[j];
    } else {
      const float* s = (const float*)en.src + idx;
#pragma unroll
      for (int j = 0; j < 8; ++j) v[j] = s[j];
    }
    float* o = (float*)en.dst + idx;
#pragma unroll
    for (int j = 0; j < 8; ++j) o[j] = v[j];
  } else {
    if (isb) {
      uint4 x = *(const uint4*)((const char*)en.src + (size_t)idx * 2);
      *(uint4*)((char*)en.dst + (size_t)idx * 2) = x;
    } else {
      const float* s = (const float*)en.src + idx;
      bf16x8 o;
#pragma unroll
      for (int j = 0; j < 8; ++j) o[j] = (__bf16)s[j];
      *(bf16x8*)((__bf16*)en.dst + idx) = o;
    }
  }
}

__global__ __launch_bounds__(256) void cvt_add(const void* __restrict__ a, const void* __restrict__ b,
                                               const int* __restrict__ flag,
                                               bf16* __restrict__ a_b, bf16* __restrict__ b_b,
                                               bf16* __restrict__ sum, int n8) {
  int i = blockIdx.x * 256 + threadIdx.x;
  if (i >= n8) return;
  const bool isb = (*flag != 0);
  float va[8], vb[8];
  bf16x8 ab, bb;
  if (isb) {
    ab = *(const bf16x8*)((const __bf16*)a + (size_t)i * 8);
    bb = *(const bf16x8*)((const __bf16*)b + (size_t)i * 8);
#pragma unroll
    for (int j = 0; j < 8; ++j) { va[j] = (float)ab[j]; vb[j] = (float)bb[j]; }
  } else {
    const float* pa = (const float*)a + (size_t)i * 8;
    const float* pb = (const float*)b + (size_t)i * 8;
#pragma unroll
    for (int j = 0; j < 8; ++j) { va[j] = pa[j]; vb[j] = pb[j]; ab[j] = (__bf16)va[j]; bb[j] = (__bf16)vb[j]; }
  }
  bf16x8 sb;
#pragma unroll
  for (int j = 0; j < 8; ++j) sb[j] = (__bf16)(va[j] + vb[j]);
  if (a_b) *(bf16x8*)((__bf16*)a_b + (size_t)i * 8) = ab;
  if (b_b) *(bf16x8*)((__bf16*)b_b + (size_t)i * 8) = bb;
  *(bf16x8*)((__bf16*)sum + (size_t)i * 8) = sb;
}

// ---------- GEMM 64x64 tile, BK=64, XCD swizzle ----------
template<int ACT, int OUTB, int RESM>
__global__ __launch_bounds__(256, 2) void gemm_bt(
    const bf16* __restrict__ A, int lda,
    const bf16* __restrict__ Wt,
    const bf16* __restrict__ bias,
    const void* __restrict__ res,
    void* __restrict__ out, int ldo,
    int M, int N, int K)
{
  __shared__ __bf16 As[2][64 * 32];
  __shared__ __bf16 Bs[2][64 * 32];
  const int gy = gridDim.y;
  const int nwg = gridDim.x * gy;
  const int t = xcd_swz(blockIdx.y * gridDim.x + blockIdx.x, nwg);
  const int m0 = (t / gy) * 64;
  const int n0 = (t % gy) * 64;
  const int tid = threadIdx.x;
  const int lane = tid & 63, wid = tid >> 6;
  const int wm = (wid >> 1) * 32, wn = (wid & 1) * 32;
  f32x4 acc[2][2] = {};
  const int lr = tid >> 2;
  const int lc = (tid & 3) * 8;
  const bf16* Ap = A + (size_t)(m0 + lr) * lda + lc;
  const bf16* Wp = Wt + (size_t)(n0 + lr) * K + lc;
  const int fr = lane & 15, ks = (lane >> 4) * 8;

  for (int k0 = 0; k0 < K; k0 += 64) {
    __syncthreads();
#pragma unroll
    for (int kk = 0; kk < 2; ++kk) {
      const int kc = k0 + kk * 32;
      gload16((const __bf16*)Ap + kc, &As[kk][8 * tid]);
      gload16((const __bf16*)Wp + kc, &Bs[kk][8 * tid]);
    }
    __syncthreads();
#pragma unroll
    for (int kk = 0; kk < 2; ++kk) {
      bf16x8 a0 = *(const bf16x8*)&As[kk][(wm + fr) * 32 + ks];
      bf16x8 a1 = *(const bf16x8*)&As[kk][(wm + 16 + fr) * 32 + ks];
      bf16x8 b0 = *(const bf16x8*)&Bs[kk][(wn + fr) * 32 + ks];
      bf16x8 b1 = *(const bf16x8*)&Bs[kk][(wn + 16 + fr) * 32 + ks];
      acc[0][0] = __builtin_amdgcn_mfma_f32_16x16x32_bf16(a0, b0, acc[0][0], 0, 0, 0);
      acc[0][1] = __builtin_amdgcn_mfma_f32_16x16x32_bf16(a0, b1, acc[0][1], 0, 0, 0);
      acc[1][0] = __builtin_amdgcn_mfma_f32_16x16x32_bf16(a1, b0, acc[1][0], 0, 0, 0);
      acc[1][1] = __builtin_amdgcn_mfma_f32_16x16x32_bf16(a1, b1, acc[1][1], 0, 0, 0);
    }
  }

  const int rq = (lane >> 4) * 4;
#pragma unroll
  for (int fm = 0; fm < 2; ++fm)
#pragma unroll
  for (int fn = 0; fn < 2; ++fn) {
    int ncol = n0 + wn + fn * 16 + fr;
    if (ncol >= N) continue;
    float bvs = (float)bias[ncol];
#pragma unroll
    for (int i = 0; i < 4; ++i) {
      int mrow = m0 + wm + fm * 16 + rq + i;
      if (mrow >= M) continue;
      float v = acc[fm][fn][i] + bvs;
      if (RESM == 1) v += (float)((const bf16*)res)[(size_t)mrow * ldo + ncol];
      else if (RESM == 2) v += ((const float*)res)[(size_t)mrow * ldo + ncol];
      if (ACT == 1) v = fmaxf(v, 0.f);
      else if (ACT == 2) v = 0.5f * v * (1.f + erff(v * 0.7071067811865476f));
      else if (ACT == 3) v = 1.f / (1.f + __expf(-v));
      if (OUTB) ((bf16*)out)[(size_t)mrow * ldo + ncol] = (bf16)v;
      else ((float*)out)[(size_t)mrow * ldo + ncol] = v;
    }
  }
}

// ---------- GEMM 64x64 tile: A = A1 + A2 (reg-staged, row-clamped, dtype-dyn) ----------
template<int ADYN>
__global__ __launch_bounds__(256, 2) void gemm_bt_add(
    const void* __restrict__ A1, const void* __restrict__ A2, int lda,
    const bf16* __restrict__ Wt, const bf16* __restrict__ bias,
    float* __restrict__ out, int ldo, int M, int N, int K,
    const int* __restrict__ flagp)
{
  __shared__ __bf16 As[2][64 * 32];
  __shared__ __bf16 Bs[2][64 * 32];
  const int gy = gridDim.y;
  const int nwg = gridDim.x * gy;
  const int t = xcd_swz(blockIdx.y * gridDim.x + blockIdx.x, nwg);
  const int m0 = (t / gy) * 64;
  const int n0 = (t % gy) * 64;
  const int tid = threadIdx.x;
  const int lane = tid & 63, wid = tid >> 6;
  const int wm = (wid >> 1) * 32, wn = (wid & 1) * 32;
  f32x4 acc[2][2] = {};
  const int lr = tid >> 2;
  const int lc = (tid & 3) * 8;
  const int ar = min(m0 + lr, M - 1);
  const size_t abase = (size_t)ar * lda + lc;
  const bf16* Wp = Wt + (size_t)(n0 + lr) * K + lc;
  const bool isb = ADYN ? (*flagp != 0) : true;
  const int fr = lane & 15, ks = (lane >> 4) * 8;

  for (int k0 = 0; k0 < K; k0 += 64) {
    bf16x8 av[2];
#pragma unroll
    for (int kk = 0; kk < 2; ++kk)
      av[kk] = ld8_add_dyn(A1, A2, abase + k0 + kk * 32, isb);
    __syncthreads();
#pragma unroll
    for (int kk = 0; kk < 2; ++kk) {
      *(bf16x8*)&As[kk][8 * tid] = av[kk];
      gload16((const __bf16*)Wp + k0 + kk * 32, &Bs[kk][8 * tid]);
    }
    __syncthreads();
#pragma unroll
    for (int kk = 0; kk < 2; ++kk) {
      bf16x8 a0 = *(const bf16x8*)&As[kk][(wm + fr) * 32 + ks];
      bf16x8 a1 = *(const bf16x8*)&As[kk][(wm + 16 + fr) * 32 + ks];
      bf16x8 b0 = *(const bf16x8*)&Bs[kk][(wn + fr) * 32 + ks];
      bf16x8 b1 = *(const bf16x8*)&Bs[kk][(wn + 16 + fr) * 32 + ks];
      acc[0][0] = __builtin_amdgcn_mfma_f32_16x16x32_bf16(a0, b0, acc[0][0], 0, 0, 0);
      acc[0][1] = __builtin_amdgcn_mfma_f32_16x16x32_bf16(a0, b1, acc[0][1], 0, 0, 0);
      acc[1][0] = __builtin_amdgcn_mfma_f32_16x16x32_bf16(a1, b0, acc[1][0], 0, 0, 0);
      acc[1][1] = __builtin_amdgcn_mfma_f32_16x16x32_bf16(a1, b1, acc[1][1], 0, 0, 0);
    }
  }

  const int rq = (lane >> 4) * 4;
#pragma unroll
  for (int fm = 0; fm < 2; ++fm)
#pragma unroll
  for (int fn = 0; fn < 2; ++fn) {
    int ncol = n0 + wn + fn * 16 + fr;
    if (ncol >= N) continue;
    float bvs = (float)bias[ncol];
#pragma unroll
    for (int i = 0; i < 4; ++i) {
      int mrow = m0 + wm + fm * 16 + rq + i;
      if (mrow >= M) continue;
      out[(size_t)mrow * ldo + ncol] = acc[fm][fn][i] + bvs;
    }
  }
}

// ---------- GEMM 128x128 tile, BK=64, XCD swizzle (A via gload16) ----------
template<int ACT, int OUTB, int RESM, int EMIT>
__global__ __launch_bounds__(256, 2) void gemm128(
    const bf16* __restrict__ A, int lda,
    const bf16* __restrict__ Wt,
    const bf16* __restrict__ bias,
    const void* __restrict__ res,
    void* __restrict__ out, int ldo,
    int M, int N, int K,
    const int* __restrict__ flagp, void* __restrict__ ob, long long eoff)
{
  __shared__ __bf16 As[2][128 * 32];
  __shared__ __bf16 Bs[2][128 * 32];
  const int gy = gridDim.y;
  const int nwg = gridDim.x * gy;
  const int t = xcd_swz(blockIdx.y * gridDim.x + blockIdx.x, nwg);
  const int m0 = (t / gy) * 128;
  const int n0 = (t % gy) * 128;
  const int tid = threadIdx.x;
  const int lane = tid & 63, wid = tid >> 6;
  const int wr = (wid >> 1) * 64, wc = (wid & 1) * 64;
  const int fr = lane & 15, ks = (lane >> 4) * 8;
  f32x4 acc[4][4] = {};

  const int srow = tid >> 2;
  const int scol = (tid & 3) * 8;
  const bf16* Ap0 = A + (size_t)(m0 + srow) * lda + scol;
  const bf16* Ap1 = A + (size_t)(m0 + 64 + srow) * lda + scol;
  const bf16* Bp0 = Wt + (size_t)(n0 + srow) * K + scol;
  const bf16* Bp1 = Wt + (size_t)(n0 + 64 + srow) * K + scol;

  for (int k0 = 0; k0 < K; k0 += 64) {
    __syncthreads();
#pragma unroll
    for (int kk = 0; kk < 2; ++kk) {
      const int kc = k0 + kk * 32;
      gload16((const __bf16*)Ap0 + kc, &As[kk][8 * tid]);
      gload16((const __bf16*)Ap1 + kc, &As[kk][64 * 32 + 8 * tid]);
      gload16((const __bf16*)Bp0 + kc, &Bs[kk][8 * tid]);
      gload16((const __bf16*)Bp1 + kc, &Bs[kk][64 * 32 + 8 * tid]);
    }
    __syncthreads();
#pragma unroll
    for (int kk = 0; kk < 2; ++kk) {
      bf16x8 af[4], bfv[4];
#pragma unroll
      for (int m = 0; m < 4; ++m) af[m]  = *(const bf16x8*)&As[kk][(wr + m * 16 + fr) * 32 + ks];
#pragma unroll
      for (int n = 0; n < 4; ++n) bfv[n] = *(const bf16x8*)&Bs[kk][(wc + n * 16 + fr) * 32 + ks];
#pragma unroll
      for (int m = 0; m < 4; ++m)
#pragma unroll
        for (int n = 0; n < 4; ++n)
          acc[m][n] = __builtin_amdgcn_mfma_f32_16x16x32_bf16(af[m], bfv[n], acc[m][n], 0, 0, 0);
    }
  }

  const bool isb = EMIT ? (*flagp != 0) : false;
  const int rq = (lane >> 4) * 4;
#pragma unroll
  for (int m = 0; m < 4; ++m) {
    const int mb = m0 + wr + m * 16 + rq;
#pragma unroll
    for (int n = 0; n < 4; ++n) {
      const int ncol = n0 + wc + n * 16 + fr;
      const float bvs = (float)bias[ncol];
#pragma unroll
      for (int i = 0; i < 4; ++i) {
        const int mrow = mb + i;
        if (mrow >= M) continue;
        float v = acc[m][n][i] + bvs;
        if (RESM == 1) v += (float)((const bf16*)res)[(size_t)mrow * ldo + ncol];
        else if (RESM == 2) v += ((const float*)res)[(size_t)mrow * ldo + ncol];
        if (ACT == 1) v = fmaxf(v, 0.f);
        else if (ACT == 2) v = 0.5f * v * (1.f + erff(v * 0.7071067811865476f));
        else if (ACT == 3) v = 1.f / (1.f + __expf(-v));
        if (OUTB) ((bf16*)out)[(size_t)mrow * ldo + ncol] = (bf16)v;
        else ((float*)out)[(size_t)mrow * ldo + ncol] = v;
        if (EMIT) {
          long long eo = eoff + (long long)mrow * ldo + ncol;
          if (isb) ((__bf16*)ob)[eo] = (__bf16)v;
          else ((float*)ob)[eo] = v;
        }
      }
    }
  }
}

// ---------- Gate pair: z in {det,seg}; A = proj + z*256; sigmoid; d_out only ----------
__global__ __launch_bounds__(256, 2) void gemm_gate2(
    const bf16* __restrict__ proj,     // [M,512]
    const bf16* __restrict__ W0, const bf16* __restrict__ b0,
    const bf16* __restrict__ W1, const bf16* __restrict__ b1,
    void* __restrict__ ob, long long eo0, long long eo1,
    int M, const int* __restrict__ flagp)
{
  constexpr int K = 256, ldaP = 512;
  __shared__ __bf16 As[2][128 * 32];
  __shared__ __bf16 Bs[2][128 * 32];
  const bf16* Wt = blockIdx.z ? W1 : W0;
  const bf16* bias = blockIdx.z ? b1 : b0;
  const long long eoff = blockIdx.z ? eo1 : eo0;
  const bf16* A = proj + (blockIdx.z ? 256 : 0);
  const int gy = gridDim.y;
  const int nwg = gridDim.x * gy;
  const int t = xcd_swz(blockIdx.y * gridDim.x + blockIdx.x, nwg);
  const int m0 = (t / gy) * 128;
  const int n0 = (t % gy) * 128;
  const int tid = threadIdx.x;
  const int lane = tid & 63, wid = tid >> 6;
  const int wr = (wid >> 1) * 64, wc = (wid & 1) * 64;
  const int fr = lane & 15, ks = (lane >> 4) * 8;
  f32x4 acc[4][4] = {};

  const int srow = tid >> 2;
  const int scol = (tid & 3) * 8;
  const bf16* Ap0 = A + (size_t)(m0 + srow) * ldaP + scol;
  const bf16* Ap1 = A + (size_t)(m0 + 64 + srow) * ldaP + scol;
  const bf16* Bp0 = Wt + (size_t)(n0 + srow) * K + scol;
  const bf16* Bp1 = Wt + (size_t)(n0 + 64 + srow) * K + scol;

  for (int k0 = 0; k0 < K; k0 += 64) {
    __syncthreads();
#pragma unroll
    for (int kk = 0; kk < 2; ++kk) {
      const int kc = k0 + kk * 32;
      gload16((const __bf16*)Ap0 + kc, &As[kk][8 * tid]);
      gload16((const __bf16*)Ap1 + kc, &As[kk][64 * 32 + 8 * tid]);
      gload16((const __bf16*)Bp0 + kc, &Bs[kk][8 * tid]);
      gload16((const __bf16*)Bp1 + kc, &Bs[kk][64 * 32 + 8 * tid]);
    }
    __syncthreads();
#pragma unroll
    for (int kk = 0; kk < 2; ++kk) {
      bf16x8 af[4], bfv[4];
#pragma unroll
      for (int m = 0; m < 4; ++m) af[m]  = *(const bf16x8*)&As[kk][(wr + m * 16 + fr) * 32 + ks];
#pragma unroll
      for (int n = 0; n < 4; ++n) bfv[n] = *(const bf16x8*)&Bs[kk][(wc + n * 16 + fr) * 32 + ks];
#pragma unroll
      for (int m = 0; m < 4; ++m)
#pragma unroll
        for (int n = 0; n < 4; ++n)
          acc[m][n] = __builtin_amdgcn_mfma_f32_16x16x32_bf16(af[m], bfv[n], acc[m][n], 0, 0, 0);
    }
  }

  const bool isb = (*flagp != 0);
  const int rq = (lane >> 4) * 4;
#pragma unroll
  for (int m = 0; m < 4; ++m) {
    const int mb = m0 + wr + m * 16 + rq;
#pragma unroll
    for (int n = 0; n < 4; ++n) {
      const int ncol = n0 + wc + n * 16 + fr;
      const float bvs = (float)bias[ncol];
#pragma unroll
      for (int i = 0; i < 4; ++i) {
        const int mrow = mb + i;
        if (mrow >= M) continue;
        float v = 1.f / (1.f + __expf(-(acc[m][n][i] + bvs)));
        long long eo = eoff + (long long)mrow * 256 + ncol;
        if (isb) ((__bf16*)ob)[eo] = (__bf16)v;
        else ((float*)ob)[eo] = v;
      }
    }
  }
}

// ---------- GEMM 128x128, reg-staged A (row-clamped): OP=0 A=S, OP=1 A=S*G ----------
// GDYN: gates read from gbase (d_out) at element offsets geo0/geo1 with dynamic dtype.
template<int OP, int SDYN, int GDYN>
__global__ __launch_bounds__(256, 2) void gemm128_rs(
    const void* __restrict__ S, const void* __restrict__ gbase,
    long long geo0, long long geo1,
    int lda,
    const bf16* __restrict__ Wt, const bf16* __restrict__ bias,
    bf16* __restrict__ out0, bf16* __restrict__ out1, int ldo,
    int M, int N, int K, const int* __restrict__ flagp)
{
  __shared__ __bf16 As[2][128 * 32];
  __shared__ __bf16 Bs[2][128 * 32];
  const long long geo = blockIdx.z ? geo1 : geo0;
  bf16* out = blockIdx.z ? out1 : out0;
  const int gy = gridDim.y;
  const int nwg = gridDim.x * gy;
  const int t = xcd_swz(blockIdx.y * gridDim.x + blockIdx.x, nwg);
  const int m0 = (t / gy) * 128;
  const int n0 = (t % gy) * 128;
  const int tid = threadIdx.x;
  const int lane = tid & 63, wid = tid >> 6;
  const int wr = (wid >> 1) * 64, wc = (wid & 1) * 64;
  const int fr = lane & 15, ks = (lane >> 4) * 8;
  f32x4 acc[4][4] = {};

  const int srow = tid >> 2;
  const int scol = (tid & 3) * 8;
  const int r0 = min(m0 + srow, M - 1);
  const int r1 = min(m0 + 64 + srow, M - 1);
  const size_t s0off = (size_t)r0 * lda + scol;
  const size_t s1off = (size_t)r1 * lda + scol;
  const bf16* Bp0 = Wt + (size_t)(n0 + srow) * K + scol;
  const bf16* Bp1 = Wt + (size_t)(n0 + 64 + srow) * K + scol;
  const bool isb = (SDYN || GDYN) ? (*flagp != 0) : true;
  const bool isbS = SDYN ? isb : true;
  const bool isbG = GDYN ? isb : true;

  for (int k0 = 0; k0 < K; k0 += 64) {
    bf16x8 a0[2], a1[2];
#pragma unroll
    for (int kk = 0; kk < 2; ++kk) {
      const int kc = kk * 32 + k0;
      bf16x8 s0 = ld8_dyn(S, s0off + kc, isbS);
      bf16x8 s1 = ld8_dyn(S, s1off + kc, isbS);
      if (OP == 1) {
        float g0[8], g1[8];
        ld8f_dyn(gbase, (size_t)geo + s0off + kc, isbG, g0);
        ld8f_dyn(gbase, (size_t)geo + s1off + kc, isbG, g1);
#pragma unroll
        for (int j = 0; j < 8; ++j) {
          a0[kk][j] = (__bf16)((float)s0[j] * g0[j]);
          a1[kk][j] = (__bf16)((float)s1[j] * g1[j]);
        }
      } else {
        a0[kk] = s0;
        a1[kk] = s1;
      }
    }
    __syncthreads();
#pragma unroll
    for (int kk = 0; kk < 2; ++kk) {
      const int kc = kk * 32 + k0;
      *(bf16x8*)&As[kk][8 * tid] = a0[kk];
      *(bf16x8*)&As[kk][64 * 32 + 8 * tid] = a1[kk];
      gload16((const __bf16*)Bp0 + kc, &Bs[kk][8 * tid]);
      gload16((const __bf16*)Bp1 + kc, &Bs[kk][64 * 32 + 8 * tid]);
    }
    __syncthreads();
#pragma unroll
    for (int kk = 0; kk < 2; ++kk) {
      bf16x8 af[4], bfv[4];
#pragma unroll
      for (int m = 0; m < 4; ++m) af[m]  = *(const bf16x8*)&As[kk][(wr + m * 16 + fr) * 32 + ks];
#pragma unroll
      for (int n = 0; n < 4; ++n) bfv[n] = *(const bf16x8*)&Bs[kk][(wc + n * 16 + fr) * 32 + ks];
#pragma unroll
      for (int m = 0; m < 4; ++m)
#pragma unroll
        for (int n = 0; n < 4; ++n)
          acc[m][n] = __builtin_amdgcn_mfma_f32_16x16x32_bf16(af[m], bfv[n], acc[m][n], 0, 0, 0);
    }
  }

  const int rq = (lane >> 4) * 4;
#pragma unroll
  for (int m = 0; m < 4; ++m) {
    const int mb = m0 + wr + m * 16 + rq;
#pragma unroll
    for (int n = 0; n < 4; ++n) {
      const int ncol = n0 + wc + n * 16 + fr;
      const float bvs = (float)bias[ncol];
#pragma unroll
      for (int i = 0; i < 4; ++i) {
        const int mrow = mb + i;
        if (mrow >= M) continue;
        out[(size_t)mrow * ldo + ncol] = (bf16)(acc[m][n][i] + bvs);
      }
    }
  }
}

// ---------- Fused GEMM (N==256) + bias + residual + LayerNorm; BK=64 ----------
template<int RESM, int EMIT, int OUTF>
__global__ __launch_bounds__(256, 2) void gemm_ln(
    const bf16* __restrict__ A, int lda,
    const bf16* __restrict__ Wt,
    const bf16* __restrict__ bias,
    const void* __restrict__ res,
    const bf16* __restrict__ g, const bf16* __restrict__ b,
    bf16* __restrict__ outb, float* __restrict__ outf,
    int M, int K,
    const int* __restrict__ flagp, void* __restrict__ ob, long long eoff)
{
  __shared__ __bf16 As[2][64 * 32];
  __shared__ __bf16 Bs[2][256 * 32];
  __shared__ float redS[4][64], redQ[4][64];
  const int m0 = blockIdx.x * 64;
  const int tid = threadIdx.x, lane = tid & 63, wid = tid >> 6;
  const int wc = wid * 64;
  const int fr = lane & 15, ks = (lane >> 4) * 8;
  f32x4 acc[4][4] = {};
  const int srow = tid >> 2, scol = (tid & 3) * 8;
  const bf16* Ap = A + (size_t)(m0 + srow) * lda + scol;
  const bf16* Bp = Wt + (size_t)srow * K + scol;

  for (int k0 = 0; k0 < K; k0 += 64) {
    __syncthreads();
#pragma unroll
    for (int kk = 0; kk < 2; ++kk) {
      const int kc = k0 + kk * 32;
      gload16((const __bf16*)Ap + kc, &As[kk][8 * tid]);
#pragma unroll
      for (int j = 0; j < 4; ++j)
        gload16((const __bf16*)(Bp + (size_t)j * 64 * K) + kc, &Bs[kk][j * 64 * 32 + 8 * tid]);
    }
    __syncthreads();
#pragma unroll
    for (int kk = 0; kk < 2; ++kk) {
      bf16x8 af[4], bfv[4];
#pragma unroll
      for (int m = 0; m < 4; ++m) af[m]  = *(const bf16x8*)&As[kk][(m * 16 + fr) * 32 + ks];
#pragma unroll
      for (int n = 0; n < 4; ++n) bfv[n] = *(const bf16x8*)&Bs[kk][(wc + n * 16 + fr) * 32 + ks];
#pragma unroll
      for (int m = 0; m < 4; ++m)
#pragma unroll
        for (int n = 0; n < 4; ++n)
          acc[m][n] = __builtin_amdgcn_mfma_f32_16x16x32_bf16(af[m], bfv[n], acc[m][n], 0, 0, 0);
    }
  }

  const int rq = (lane >> 4) * 4;
  const bool fb = (EMIT || RESM == 3) ? (*flagp != 0) : false;
  float bvals[4], gvals[4], bb2[4];
#pragma unroll
  for (int n = 0; n < 4; ++n) {
    bvals[n] = (float)bias[wc + n * 16 + fr];
    gvals[n] = (float)g[wc + n * 16 + fr];
    bb2[n]   = (float)b[wc + n * 16 + fr];
  }
#pragma unroll
  for (int m = 0; m < 4; ++m)
#pragma unroll
  for (int i = 0; i < 4; ++i) {
    const int mrow = m0 + m * 16 + rq + i;
    const int rr = mrow < M ? mrow : M - 1;
#pragma unroll
    for (int n = 0; n < 4; ++n) {
      const size_t ri = (size_t)rr * 256 + wc + n * 16 + fr;
      float r;
      if (RESM == 1) r = (float)((const bf16*)res)[ri];
      else if (RESM == 2) r = ((const float*)res)[ri];
      else r = fb ? (float)((const bf16*)res)[ri] : ((const float*)res)[ri];
      acc[m][n][i] += bvals[n] + r;
    }
    float s = acc[m][0][i] + acc[m][1][i] + acc[m][2][i] + acc[m][3][i];
    float q = acc[m][0][i] * acc[m][0][i] + acc[m][1][i] * acc[m][1][i]
            + acc[m][2][i] * acc[m][2][i] + acc[m][3][i] * acc[m][3][i];
#pragma unroll
    for (int off = 1; off <= 8; off <<= 1) {
      s += __shfl_xor(s, off);
      q += __shfl_xor(q, off);
    }
    if (fr == 0) { redS[wid][m * 16 + rq + i] = s; redQ[wid][m * 16 + rq + i] = q; }
  }
  __syncthreads();
#pragma unroll
  for (int m = 0; m < 4; ++m)
#pragma unroll
  for (int i = 0; i < 4; ++i) {
    const int rl = m * 16 + rq + i;
    const int mrow = m0 + rl;
    if (mrow >= M) continue;
    float ts = redS[0][rl] + redS[1][rl] + redS[2][rl] + redS[3][rl];
    float tq = redQ[0][rl] + redQ[1][rl] + redQ[2][rl] + redQ[3][rl];
    float mean = ts * (1.f / 256.f);
    float var = tq * (1.f / 256.f) - mean * mean;
    float rstd = rsqrtf(var + 1e-5f);
#pragma unroll
    for (int n = 0; n < 4; ++n) {
      const int col = wc + n * 16 + fr;
      float y = (acc[m][n][i] - mean) * rstd * gvals[n] + bb2[n];
      if (outb) outb[(size_t)mrow * 256 + col] = (bf16)y;
      if (OUTF) outf[(size_t)mrow * 256 + col] = y;
      if (EMIT) {
        long long eo = eoff + (long long)mrow * 256 + col;
        if (fb) ((__bf16*)ob)[eo] = (__bf16)y;
        else ((float*)ob)[eo] = y;
      }
    }
  }
}

// ---------- MSDA sampling: 1 wave/query; valA/valB split; optional XCD swizzle ----------
__global__ __launch_bounds__(256) void msda_sample4(
    const float* __restrict__ oa,
    const float* __restrict__ rpf, int rp_base, int qcnt4, int lqrow, int split,
    const bf16* __restrict__ valA, const bf16* __restrict__ valB,
    bf16* __restrict__ out, int swz) {
  int blk = blockIdx.x;
  if (swz) blk = xcd_swz(blk, gridDim.x);
  int b = blk / qcnt4;
  int wid = threadIdx.x >> 6, lane = threadIdx.x & 63;
  int qi = (blk % qcnt4) * 4 + wid;
  size_t row = (size_t)b * lqrow + qi;
  int h = lane >> 3, d0 = (lane & 7) * 4;
  const bf16* val = (qi < split) ? valA : valB;
  const __bf16* vb = (const __bf16*)val + (size_t)b * LSRC * 256 + h * 32 + d0;
  float rx = rpf[((size_t)b * RP_STRIDE + rp_base + qi) * 2 + 0];
  float ry = rpf[((size_t)b * RP_STRIDE + rp_base + qi) * 2 + 1];
  const float* offp = oa + row * 96 + h * 8;
  const float* awp  = oa + row * 96 + 64 + h * 4;
  float a0 = awp[0], a1 = awp[1], a2 = awp[2], a3 = awp[3];
  float mx = fmaxf(fmaxf(a0, a1), fmaxf(a2, a3));
  float e0 = __expf(a0 - mx), e1 = __expf(a1 - mx), e2 = __expf(a2 - mx), e3 = __expf(a3 - mx);
  float rs = 1.f / (e0 + e1 + e2 + e3);
  float aws[4] = { e0 * rs, e1 * rs, e2 * rs, e3 * rs };
  float o0 = 0.f, o1 = 0.f, o2 = 0.f, o3 = 0.f;
#pragma unroll
  for (int p = 0; p < 4; ++p) {
    float x = rx * IMGW + offp[p * 2 + 0] - 0.5f;
    float y = ry * IMGH + offp[p * 2 + 1] - 0.5f;
    float x0f = floorf(x), y0f = floorf(y);
    float lx = x - x0f, ly = y - y0f;
    int x0 = (int)x0f, y0 = (int)y0f;
#pragma unroll
    for (int dy = 0; dy < 2; ++dy)
#pragma unroll
    for (int dx = 0; dx < 2; ++dx) {
      int xi = x0 + dx, yi = y0 + dy;
      if (xi >= 0 && xi < IW && yi >= 0 && yi < IH) {
        float wgt = aws[p] * (dx ? lx : 1.f - lx) * (dy ? ly : 1.f - ly);
        bf16x4 gv = *(const bf16x4*)(vb + (size_t)(yi * IW + xi) * 256);
        o0 += wgt * (float)gv[0]; o1 += wgt * (float)gv[1];
        o2 += wgt * (float)gv[2]; o3 += wgt * (float)gv[3];
      }
    }
  }
  bf16x4 ov;
  ov[0] = (__bf16)o0; ov[1] = (__bf16)o1; ov[2] = (__bf16)o2; ov[3] = (__bf16)o3;
  *(bf16x4*)((__bf16*)out + row * 256 + h * 32 + d0) = ov;
}

// ---------- small MHA: grid = 2*8*75, 4 queries/block ----------
__global__ __launch_bounds__(256) void mha_attn(
    const float* __restrict__ qk,
    const float* __restrict__ v,
    bf16* __restrict__ o) {
  __shared__ float probs[4][304];
  int bh = blockIdx.x / 75;
  int j  = blockIdx.x % 75;
  int b = bh >> 3, h = bh & 7;
  int wid = threadIdx.x >> 6, lane = threadIdx.x & 63;
  const float scale = 0.17677669529663687f;
  int q = j * 4 + wid;
  const float* qv = qk + ((size_t)(b * 300 + q)) * 512 + h * 32;
  float p[5];
  float mx = -1e30f;
#pragma unroll
  for (int s5 = 0; s5 < 5; ++s5) {
    int k = lane + 64 * s5;
    float sacc = -1e30f;
    if (k < 300) {
      const float* kv = qk + ((size_t)(b * 300 + k)) * 512 + 256 + h * 32;
      float sd = 0.f;
#pragma unroll
      for (int dd = 0; dd < 32; ++dd) sd += qv[dd] * kv[dd];
      sacc = sd * scale;
    }
    p[s5] = sacc;
    mx = fmaxf(mx, sacc);
  }
#pragma unroll
  for (int off = 32; off; off >>= 1) mx = fmaxf(mx, __shfl_xor(mx, off));
  float ssum = 0.f;
#pragma unroll
  for (int s5 = 0; s5 < 5; ++s5) {
    p[s5] = (p[s5] > -1e29f) ? __expf(p[s5] - mx) : 0.f;
    ssum += p[s5];
  }
#pragma unroll
  for (int off = 32; off; off >>= 1) ssum += __shfl_xor(ssum, off);
  float rinv = 1.f / ssum;
#pragma unroll
  for (int s5 = 0; s5 < 5; ++s5) {
    int k = lane + 64 * s5;
    if (k < 300) probs[wid][k] = p[s5] * rinv;
  }
  __syncthreads();
  {
    int d = lane & 31, half = lane >> 5;
    float acc = 0.f;
    for (int k = half * 150; k < half * 150 + 150; ++k)
      acc += probs[wid][k] * v[((size_t)(b * 300 + k)) * 256 + h * 32 + d];
    acc += __shfl_xor(acc, 32);
    if (lane < 32) o[((size_t)(b * 300 + q)) * 256 + h * 32 + d] = (bf16)acc;
  }
}

extern "C" void kernel_launch(void* const* d_in, const int* in_sizes, int n_in,
                              void* d_out, int out_size, void* d_ws, size_t ws_size,
                              hipStream_t stream) {
  (void)n_in; (void)out_size; (void)ws_size;
  const size_t SZ = (size_t)MS * D * sizeof(bf16);   // 33,177,600

  char* w = (char*)d_ws;
  auto carve = [&](size_t bytes) { char* p = w; w += (bytes + 255) & ~(size_t)255; return p; };

  int*   flag = (int*)carve(256);
  float* rp_f = (float*)carve((size_t)NB * RP_STRIDE * 2 * 4);

  bf16* wb[51] = {};
  bf16* wcat_s = nullptr; bf16* bcat_s = nullptr;
  bf16* wcat_q = nullptr; bf16* bcat_q = nullptr;
  for (int i = 7; i <= 50; ++i) {
    if (i == 9)       { wcat_s = (bf16*)carve((size_t)96 * 256 * 2); wb[9]  = wcat_s; }
    else if (i == 10) { bcat_s = (bf16*)carve(96 * 2);               wb[10] = bcat_s; }
    else if (i == 11) { wb[11] = wcat_s + 64 * 256; }
    else if (i == 12) { wb[12] = bcat_s + 64; }
    else if (i == 17) { wcat_q = (bf16*)carve((size_t)96 * 256 * 2); wb[17] = wcat_q; }
    else if (i == 18) { bcat_q = (bf16*)carve(96 * 2);               wb[18] = bcat_q; }
    else if (i == 19) { wb[19] = wcat_q + 64 * 256; }
    else if (i == 20) { wb[20] = bcat_q + 64; }
    else wb[i] = (bf16*)carve((size_t)in_sizes[i] * 2);
  }

  bf16* query_b     = (bf16*)carve((size_t)MQ * D * 2);
  bf16* query_pos_b = (bf16*)carve((size_t)MQ * D * 2);
  bf16* qx_q        = (bf16*)carve((size_t)MQ * D * 2);
  bf16* att_q       = (bf16*)carve((size_t)MQ * D * 2);
  bf16* q_x         = (bf16*)carve((size_t)MQ * D * 2);
  bf16* mha_o       = (bf16*)carve((size_t)MQ * D * 2);
  bf16* lnq_b       = (bf16*)carve((size_t)MQ * D * 2);
  bf16* qh          = (bf16*)carve((size_t)MQ * 1024 * 2);
  float* qoffawb    = (float*)carve((size_t)MQ * 96 * 4);
  float* q_res      = (float*)carve((size_t)MQ * D * 4);
  float* qk_f       = (float*)carve((size_t)MQ * 512 * 4);
  float* v_f        = (float*)carve((size_t)MQ * D * 4);

  char* A = carve(SZ);   // srcout (ph2+)
  char* B = carve(SZ);   // offawb (f32 [MS,96])
  char* C = carve(SZ);   // samp -> lnx (in-place)
  char* Dd = carve(SZ);  // val(sa) -> hid(lo) -> proj(lo) -> val_det
  char* E = carve(SZ);   // hid(hi) -> proj(hi) -> val_seg
  carve(512 * 1024);     // tail pad

  const bf16* query     = (const bf16*)d_in[0];
  const bf16* query_pos = (const bf16*)d_in[1];
  const void* src       = d_in[2];
  const void* pos       = d_in[3];

  dim3 blk(256);
  const int GS64  = (MS + 63) / 64;        // 1013
  const int GQ64  = (MQ + 63) / 64;        // 10
  const int G128  = (MS + 127) / 128;      // 507

  // ---- detect + convert ----
  detect_kernel<<<1, 1, 0, stream>>>(d_in[23], flag);
  {
    CvtBatch cb{};
    int nb = 0, cnt = 0;
    auto addcvt = [&](const void* s, void* dst, int n, int f32o) {
      cb.e[cnt] = { s, dst, n, f32o };
      cb.blk0[cnt] = nb;
      nb += (n + 2047) / 2048;
      ++cnt;
    };
    addcvt(d_in[4], rp_f, in_sizes[4], 1);
    for (int i = 7; i <= 50; ++i) addcvt(d_in[i], wb[i], in_sizes[i], 0);
    cb.cnt = cnt;
    cvt_batch_kernel<<<nb, blk, 0, stream>>>(cb, flag);
  }
  cvt_add<<<MQ * D / 8 / 256, blk, 0, stream>>>(query, query_pos, flag, query_b, query_pos_b, qx_q, MQ * D / 8);

  // ---- Phase 1: self MSDA ----
  float* offawb = (float*)B;
  bf16*  val    = (bf16*)Dd;
  gemm_bt_add<1><<<dim3(GS64,2), blk, 0, stream>>>(src, pos, 256, wb[9], wb[10], offawb, 96, MS, 96, 256, flag);
  gemm128_rs<0,1,0><<<dim3(G128,2,1), blk, 0, stream>>>(src, nullptr, 0, 0, 256, wb[7], wb[8], val, nullptr, 256, MS, 256, 256, flag);
  bf16* samp = (bf16*)C;
  msda_sample4<<<NB * (LSRC / 4), blk, 0, stream>>>(offawb, rp_f, 0, LSRC / 4, LSRC, 1 << 30, val, val, samp, 1);
  bf16* lnx = (bf16*)C;
  gemm_ln<3,0,0><<<GS64, blk, 0, stream>>>(samp, 256, wb[13], wb[14], src, wb[23], wb[24],
                                           lnx, nullptr, MS, 256, flag, nullptr, 0);

  // ---- Phase 2: FFN1 in 2 chunks; hid spans Dd+E; FFN2+LN2 fused, emit d_out ----
  bf16* srcout = (bf16*)A;
  {
    const int CH = MS / 2;
    const int GC128 = (CH + 127) / 128;
    const int GC64  = (CH + 63) / 64;
    bf16* hid = (bf16*)Dd;
    for (int c = 0; c < 2; ++c) {
      size_t ro = (size_t)c * CH * 256;
      gemm128<1,1,0,0><<<dim3(GC128,8), blk, 0, stream>>>(lnx + ro, 256, wb[33], wb[34], nullptr, hid, 1024, CH, 1024, 256, nullptr, nullptr, 0);
      gemm_ln<1,1,0><<<GC64, blk, 0, stream>>>(hid, 1024, wb[35], wb[36], lnx + ro, wb[25], wb[26],
                                               srcout + ro, nullptr, CH, 1024, flag, d_out, OFF_S + (long long)ro);
    }
  }

  // ---- Phase 3: tcs proj + gate pair (one z=2 dispatch, gates -> d_out only) ----
  bf16* proj = (bf16*)Dd;      // 66 MB spans Dd+E
  gemm128<2,1,0,0><<<dim3(G128,4), blk, 0, stream>>>(srcout, 256, wb[41], wb[42], nullptr, proj, 512, MS, 512, 256, nullptr, nullptr, 0);
  gemm_gate2<<<dim3(G128,2,2), blk, 0, stream>>>(proj, wb[43], wb[44], wb[45], wb[46],
                                                 d_out, OFF_GD, OFF_GS, MS, flag);

  // ---- query off/aw ----
  gemm_bt<0,0,0><<<dim3(GQ64,2), blk, 0, stream>>>(qx_q, 256, wb[17], wb[18], nullptr, qoffawb, 96, MQ, 96, 256);

  // ---- Phase 4: gated value GEMMs (z: det/seg; gates from d_out), merged sampler ----
  bf16* val_det = (bf16*)Dd;
  bf16* val_seg = (bf16*)E;
  gemm128_rs<1,0,1><<<dim3(G128,2,2), blk, 0, stream>>>(srcout, d_out, OFF_GD, OFF_GS, 256,
                                                        wb[15], wb[16], val_det, val_seg, 256,
                                                        MS, 256, 256, flag);
  msda_sample4<<<NB * (LQ / 4), blk, 0, stream>>>(qoffawb, rp_f, LSRC, LQ / 4, LQ, NDET, val_det, val_seg, att_q, 0);

  // ---- Phase 5: ca out-proj + normq (fused) ----
  gemm_ln<1,0,1><<<GQ64, blk, 0, stream>>>(att_q, 256, wb[21], wb[22], query_b, wb[27], wb[28],
                                           q_x, q_res, MQ, 256, nullptr, nullptr, 0);

  // ---- Phase 6: query self-attention (q_x+query_pos fused into qk staging) ----
  gemm_bt_add<0><<<dim3(GQ64,8), blk, 0, stream>>>(q_x, query_pos_b, 256, wb[47], wb[48], qk_f, 512, MQ, 512, 256, flag);
  gemm_bt<0,0,0><<<dim3(GQ64,4), blk, 0, stream>>>(q_x, 256, wb[47] + (size_t)512 * 256, wb[48] + 512, nullptr, v_f, 256, MQ, 256, 256);
  mha_attn<<<NB * 8 * 75, blk, 0, stream>>>(qk_f, v_f, mha_o);
  gemm_ln<2,0,1><<<GQ64, blk, 0, stream>>>(mha_o, 256, wb[49], wb[50], q_res, wb[29], wb[30],
                                           q_x, q_res, MQ, 256, nullptr, nullptr, 0);

  // ---- Phase 7: FFN3 + norm3 (fused, emits query output) ----
  gemm_bt<1,1,0><<<dim3(GQ64,16), blk, 0, stream>>>(q_x, 256, wb[37], wb[38], nullptr, qh, 1024, MQ, 1024, 256);
  gemm_ln<2,1,0><<<GQ64, blk, 0, stream>>>(qh, 1024, wb[39], wb[40], q_res, wb[31], wb[32],
                                           lnq_b, nullptr, MQ, 1024, flag, d_out, OFF_Q);
}